// Round 17
// baseline (2158.137 us; speedup 1.0000x reference)
//
#include <hip/hip_runtime.h>

#define LAYERS 6
#define NH 16
#define DIM 1024
#define VOCAB 32000
#define SEQ 2048
#define NBATCH 2
#define HEADD 64
#define NROW (NBATCH*SEQ)   // 4096
#define FF 4096
#define QKVS 3072
#define NCB (VOCAB/256)     // 125 col-blocks in head GEMM
#define LN_EPS 1e-5f

typedef unsigned short bfu;  // bf16 bits
typedef __attribute__((ext_vector_type(8))) short s16x8;
typedef __attribute__((ext_vector_type(4))) float f32x4;

__device__ __forceinline__ float bf2f(bfu u) { return __uint_as_float(((unsigned)u) << 16); }
__device__ __forceinline__ bfu f2bf(float x) {
  unsigned u = __float_as_uint(x);
  return (bfu)((u + 0x7fffu + ((u >> 16) & 1u)) >> 16);  // RNE
}

__device__ __forceinline__ void gload16(const void* g, void* l) {
  __builtin_amdgcn_global_load_lds((const __attribute__((address_space(1))) void*)g,
                                   (__attribute__((address_space(3))) void*)l, 16, 0, 0);
}

__device__ __forceinline__ f32x4 mfma32(s16x8 a, s16x8 b, f32x4 c) {
  return __builtin_amdgcn_mfma_f32_16x16x32_bf16(a, b, c, 0, 0, 0);
}

// ---------------- transpose+convert: out[C][R] (bf16) = in[R][C]^T (fp32) ----------------
__global__ __launch_bounds__(256) void tkernel(const float* __restrict__ in,
                                               bfu* __restrict__ out, int R, int C) {
  __shared__ bfu tile[32][33];
  int tx = threadIdx.x, ty = threadIdx.y;
  int bx = blockIdx.x * 32, by = blockIdx.y * 32;
#pragma unroll
  for (int i = 0; i < 4; ++i)
    tile[ty + i * 8][tx] = f2bf(in[(size_t)(by + ty + i * 8) * C + bx + tx]);
  __syncthreads();
#pragma unroll
  for (int i = 0; i < 4; ++i)
    out[(size_t)(bx + ty + i * 8) * R + by + tx] = tile[tx][ty + i * 8];
}

// ---- merged per-layer weight transpose: qkv(3) + proj + fc1 + fc2 in ONE launch ----
__global__ __launch_bounds__(256) void wtrans_kernel(const float* __restrict__ wq,
                                                     const float* __restrict__ wk,
                                                     const float* __restrict__ wv,
                                                     const float* __restrict__ wp,
                                                     const float* __restrict__ w1,
                                                     const float* __restrict__ w2,
                                                     bfu* __restrict__ qkvT,
                                                     bfu* __restrict__ wpT,
                                                     bfu* __restrict__ f1T,
                                                     bfu* __restrict__ f2T) {
  __shared__ bfu tile[32][33];
  int bi = blockIdx.x;
  const float* in; bfu* out; int R, C, id;
  if (bi < 4096) {
    int p = bi >> 10; id = bi & 1023;
    in = p == 0 ? wq : p == 1 ? wk : p == 2 ? wv : wp;
    out = (p == 3) ? wpT : qkvT + (size_t)p * DIM * DIM;
    R = DIM; C = DIM;
  } else if (bi < 8192) {
    id = bi - 4096; in = w1; out = f1T; R = DIM; C = FF;
  } else {
    id = bi - 8192; in = w2; out = f2T; R = FF; C = DIM;
  }
  int nbx = C >> 5;
  int bx = (id % nbx) * 32, by = (id / nbx) * 32;
  int tx = threadIdx.x, ty = threadIdx.y;
#pragma unroll
  for (int i = 0; i < 4; ++i)
    tile[ty + i * 8][tx] = f2bf(in[(size_t)(by + ty + i * 8) * C + bx + tx]);
  __syncthreads();
#pragma unroll
  for (int i = 0; i < 4; ++i)
    out[(size_t)(bx + ty + i * 8) * R + by + tx] = tile[tx][ty + i * 8];
}

// ---------------- embedding ----------------
__global__ __launch_bounds__(256) void embed_kernel(const int* __restrict__ idx,
                                                    const float* __restrict__ tok,
                                                    const float* __restrict__ pos,
                                                    float* __restrict__ xf) {
  int row = blockIdx.x;
  int t = row % SEQ;
  int tokid = idx[row];
  int d0 = threadIdx.x * 4;
  float4 tv = *(const float4*)&tok[(size_t)tokid * DIM + d0];
  float4 pv = *(const float4*)&pos[(size_t)t * DIM + d0];
  float4 r;
  r.x = tv.x + pv.x; r.y = tv.y + pv.y; r.z = tv.z + pv.z; r.w = tv.w + pv.w;
  *(float4*)&xf[(size_t)row * DIM + d0] = r;
}

// ---------------- LayerNorm v2: one wave per row (no barriers, no LDS) ----------------
__global__ __launch_bounds__(256) void ln_kernel(const float* __restrict__ xf,
                                                 const float* __restrict__ gw,
                                                 const float* __restrict__ bw,
                                                 bfu* __restrict__ h) {
  const int row = blockIdx.x * 4 + (threadIdx.x >> 6);
  const int lane = threadIdx.x & 63;
  const float* xr = xf + (size_t)row * DIM;
  float4 xv[4];
  float s = 0.0f, ss = 0.0f;
#pragma unroll
  for (int j = 0; j < 4; ++j) {
    xv[j] = *(const float4*)&xr[lane * 4 + j * 256];
    s  += xv[j].x + xv[j].y + xv[j].z + xv[j].w;
    ss += xv[j].x * xv[j].x + xv[j].y * xv[j].y + xv[j].z * xv[j].z + xv[j].w * xv[j].w;
  }
#pragma unroll
  for (int o = 32; o; o >>= 1) { s += __shfl_xor(s, o); ss += __shfl_xor(ss, o); }
  float mean = s * (1.0f / DIM);
  float inv = rsqrtf(ss * (1.0f / DIM) - mean * mean + LN_EPS);
#pragma unroll
  for (int j = 0; j < 4; ++j) {
    float4 gv = *(const float4*)&gw[lane * 4 + j * 256];
    float4 bv = *(const float4*)&bw[lane * 4 + j * 256];
    ushort4 hv;
    hv.x = f2bf((xv[j].x - mean) * inv * gv.x + bv.x);
    hv.y = f2bf((xv[j].y - mean) * inv * gv.y + bv.y);
    hv.z = f2bf((xv[j].z - mean) * inv * gv.z + bv.z);
    hv.w = f2bf((xv[j].w - mean) * inv * gv.w + bv.w);
    *(ushort4*)&h[(size_t)row * DIM + lane * 4 + j * 256] = hv;
  }
}

// ---- LN with fused fc2-partial combine: x = xf + p0 + p1 + bias; xf = x; h = LN(x) ----
__global__ __launch_bounds__(256) void lnfuse_kernel(float* __restrict__ xf,
                                                     const float* __restrict__ pb,
                                                     const float* __restrict__ bias,
                                                     const float* __restrict__ gw,
                                                     const float* __restrict__ bw,
                                                     bfu* __restrict__ h) {
  const int row = blockIdx.x * 4 + (threadIdx.x >> 6);
  const int lane = threadIdx.x & 63;
  float* xr = xf + (size_t)row * DIM;
  const float* p0 = pb + (size_t)row * DIM;
  const float* p1 = pb + (size_t)NROW * DIM + (size_t)row * DIM;
  float4 xv[4];
  float s = 0.0f, ss = 0.0f;
#pragma unroll
  for (int j = 0; j < 4; ++j) {
    int i0 = lane * 4 + j * 256;
    float4 a = *(const float4*)&xr[i0];
    float4 q0 = *(const float4*)&p0[i0];
    float4 q1 = *(const float4*)&p1[i0];
    float4 bb = *(const float4*)&bias[i0];
    xv[j].x = a.x + q0.x + q1.x + bb.x;
    xv[j].y = a.y + q0.y + q1.y + bb.y;
    xv[j].z = a.z + q0.z + q1.z + bb.z;
    xv[j].w = a.w + q0.w + q1.w + bb.w;
    *(float4*)&xr[i0] = xv[j];
    s  += xv[j].x + xv[j].y + xv[j].z + xv[j].w;
    ss += xv[j].x * xv[j].x + xv[j].y * xv[j].y + xv[j].z * xv[j].z + xv[j].w * xv[j].w;
  }
#pragma unroll
  for (int o = 32; o; o >>= 1) { s += __shfl_xor(s, o); ss += __shfl_xor(ss, o); }
  float mean = s * (1.0f / DIM);
  float inv = rsqrtf(ss * (1.0f / DIM) - mean * mean + LN_EPS);
#pragma unroll
  for (int j = 0; j < 4; ++j) {
    int i0 = lane * 4 + j * 256;
    float4 gv = *(const float4*)&gw[i0];
    float4 bv = *(const float4*)&bw[i0];
    ushort4 hv;
    hv.x = f2bf((xv[j].x - mean) * inv * gv.x + bv.x);
    hv.y = f2bf((xv[j].y - mean) * inv * gv.y + bv.y);
    hv.z = f2bf((xv[j].z - mean) * inv * gv.z + bv.z);
    hv.w = f2bf((xv[j].w - mean) * inv * gv.w + bv.w);
    *(ushort4*)&h[(size_t)row * DIM + i0] = hv;
  }
}

// ---------------- GEMM 128x128xBK32, ring-2 counted-vmcnt ----------------
// MODE 0: bf16 = acc(+bias); 1: bf16 relu; 2: fp32 = resid+acc+bias;
// MODE 5: bf16 = acc, + fused V-transpose write for cols>=2048 (qkv);
// MODE 6: fp32 partial plane bz (K-split via gridDim.z; no bias/resid).
template <int MODE>
__global__ __launch_bounds__(256) void gemm_bt(const bfu* __restrict__ A,
                                               const bfu* __restrict__ Bt,
                                               const float* __restrict__ bias,
                                               const float* resid,
                                               void* outp,
                                               bfu* __restrict__ vT,
                                               int M, int N, int K, int ldk) {
  __shared__ __align__(16) char sm[32768];  // 2 bufs x (A 8K | B 8K)
  const int tid = threadIdx.x;
  const int lane = tid & 63, wave = tid >> 6;
  const int c = lane & 15, g = lane >> 4;

  const int gx = gridDim.x, gy = gridDim.y, gz = gridDim.z;
  int orig = (blockIdx.z * gy + blockIdx.y) * gx + blockIdx.x;   // dispatch order
  int nwg = gx * gy * gz;
  int cpx = nwg >> 3;
  int swz = (orig & 7) * cpx + (orig >> 3);
  int bz = swz / (gx * gy);
  int rem = swz - bz * (gx * gy);
  int by = rem / gx, bx = rem - by * gx;

  const int m0 = by * 128, n0 = bx * 128;
  const int wm = (wave & 1) * 64, wn = (wave >> 1) * 64;
  f32x4 acc[4][4] = {};
  const char* Ac = (const char*)(A + (size_t)bz * K);  // K-split offset (elements)
  const char* Bc = (const char*)(Bt + (size_t)bz * K);
  const size_t stride = (size_t)ldk * 2;

  const int g1 = tid, g2 = tid + 256;
  const int r1 = g1 >> 2, j1 = g1 & 3;
  const int r2 = g2 >> 2, j2 = g2 & 3;
  const size_t a1 = (size_t)(m0 + r1) * stride + j1 * 16;
  const size_t a2 = (size_t)(m0 + r2) * stride + j2 * 16;
  const size_t b1 = (size_t)(n0 + r1) * stride + j1 * 16;
  const size_t b2 = (size_t)(n0 + r2) * stride + j2 * 16;

  auto STAGE = [&](int kt, int buf) {
    char* base = sm + buf * 16384;
    size_t ko = (size_t)kt * 64;
    gload16(Ac + a1 + ko, base + g1 * 16);
    gload16(Ac + a2 + ko, base + g2 * 16);
    gload16(Bc + b1 + ko, base + 8192 + g1 * 16);
    gload16(Bc + b2 + ko, base + 8192 + g2 * 16);
  };

  const int NT = K >> 5;
  STAGE(0, 0);
  STAGE(1, 1);
  asm volatile("s_waitcnt vmcnt(4)" ::: "memory");
  __builtin_amdgcn_s_barrier();
  __builtin_amdgcn_sched_barrier(0);

  for (int i = 0; i < NT; ++i) {
    const char* base = sm + (i & 1) * 16384;
    s16x8 af[4], bfr[4];
#pragma unroll
    for (int mi = 0; mi < 4; ++mi)
      af[mi] = *(const s16x8*)(base + (wm + mi * 16 + c) * 64 + g * 16);
#pragma unroll
    for (int ni = 0; ni < 4; ++ni)
      bfr[ni] = *(const s16x8*)(base + 8192 + (wn + ni * 16 + c) * 64 + g * 16);
    asm volatile("s_waitcnt lgkmcnt(0)" ::: "memory");
    __builtin_amdgcn_sched_barrier(0);
    __builtin_amdgcn_s_barrier();
    __builtin_amdgcn_sched_barrier(0);
    if (i + 2 < NT) STAGE(i + 2, i & 1);
    __builtin_amdgcn_s_setprio(1);
#pragma unroll
    for (int mi = 0; mi < 4; ++mi)
#pragma unroll
      for (int ni = 0; ni < 4; ++ni)
        acc[mi][ni] = mfma32(af[mi], bfr[ni], acc[mi][ni]);
    __builtin_amdgcn_s_setprio(0);
    if (i < NT - 2) {
      asm volatile("s_waitcnt vmcnt(4)" ::: "memory");
      __builtin_amdgcn_s_barrier();
      __builtin_amdgcn_sched_barrier(0);
    } else if (i == NT - 2) {
      asm volatile("s_waitcnt vmcnt(0)" ::: "memory");
      __builtin_amdgcn_s_barrier();
      __builtin_amdgcn_sched_barrier(0);
    }
  }

#pragma unroll
  for (int mi = 0; mi < 4; ++mi) {
#pragma unroll
    for (int ni = 0; ni < 4; ++ni) {
      int col = n0 + wn + ni * 16 + c;
      float bv = (MODE != 6 && bias) ? bias[col] : 0.0f;
#pragma unroll
      for (int jj = 0; jj < 4; ++jj) {
        int row = m0 + wm + mi * 16 + g * 4 + jj;
        float val = acc[mi][ni][jj] + bv;
        size_t oi = (size_t)row * N + col;
        if (MODE == 1) val = fmaxf(val, 0.0f);
        if (MODE == 2)      ((float*)outp)[oi] = resid[oi] + val;
        else if (MODE == 6) ((float*)outp)[(size_t)bz * M * N + oi] = val;
        else {
          ((bfu*)outp)[oi] = f2bf(val);
          if (MODE == 5 && col >= 2048) {    // fused V transpose: vT[(b,h,d)][t]
            int d = col - 2048;
            int b2 = row >> 11, t = row & 2047;
            vT[((size_t)((b2 << 4) + (d >> 6)) * HEADD + (d & 63)) * SEQ + t] = f2bf(val);
          }
        }
      }
    }
  }
}

// ---------------- GEMM 256x256xBK32, 16 waves (64x64/wave), ring-2, 2 blocks/CU ----------------
// BK=32: LDS 64KB total -> 2 blocks/CU (32 waves) so one block's MFMAs hide the other's
// barrier/stage drains. Granule swizzle f(r)=(r&3)^((r>>2)&3) on stage-source AND read.
// MODE 1: bf16 relu(acc+bias); MODE 3: fp32 acc+bias; MODE 4: MODE 3 + logsumexp partials
template <int MODE>
__global__ __launch_bounds__(1024) void gemm1024(const bfu* __restrict__ A,
                                                 const bfu* __restrict__ Bt,
                                                 const float* __restrict__ bias,
                                                 const float* resid,
                                                 void* outp,
                                                 int M, int N, int K,
                                                 int colchunk,
                                                 float* __restrict__ pmax,
                                                 float* __restrict__ psum) {
  extern __shared__ char smem[];   // 2 bufs x (A 16K | B 16K) = 64KB (+8K sred for MODE 4)
  const int tid = threadIdx.x;
  const int lane = tid & 63, w = tid >> 6;
  const int c = lane & 15, g = lane >> 4;

  const int gx = gridDim.x, gy = gridDim.y;
  int orig = blockIdx.y * gx + blockIdx.x;
  int cpx = (gx * gy) >> 3;
  int swz = (orig & 7) * cpx + (orig >> 3);
  int bx, by;
  if (colchunk) { bx = swz / gy; by = swz - bx * gy; }
  else          { by = swz / gx; bx = swz - by * gx; }
  const int m0 = by * 256, n0 = bx * 256;

  const int wrow = w >> 2, wcol = w & 3;
  const size_t gstr = (size_t)K * 2;
  const char* Ag = (const char*)A + (size_t)m0 * gstr;
  const char* Bg = (const char*)Bt + (size_t)n0 * gstr;

  // staging: 1024 granules (16B) per operand per tile; thread tid covers granule tid.
  // LDS dest linear (tid*16); source granule pre-swizzled by f(srow).
  const int srow = tid >> 2;
  const int scg = (tid & 3) ^ ((srow & 3) ^ ((srow >> 2) & 3));
  const size_t ga = (size_t)srow * gstr + scg * 16;

  auto STAGE = [&](int kt, int buf) {
    char* base = smem + buf * 32768;
    size_t ko = (size_t)kt * 64;            // 32 cols * 2B
    gload16(Ag + ga + ko, base + w * 1024);
    gload16(Bg + ga + ko, base + 16384 + w * 1024);
  };

  const int NT = K >> 5;
  f32x4 acc[4][4] = {};

  STAGE(0, 0);
  STAGE(1, 1);
  asm volatile("s_waitcnt vmcnt(2)" ::: "memory");   // tile-0's 2 loads done
  __builtin_amdgcn_s_barrier();
  __builtin_amdgcn_sched_barrier(0);

  const int fc = (c & 3) ^ ((c >> 2) & 3);
  const int aoff = ((g ^ fc) << 4);          // logical granule g at physical g^f(row)

  for (int i = 0; i < NT; ++i) {
    const char* base = smem + (i & 1) * 32768;
    const char* ldsA = base + (wrow * 64 + c) * 64;
    const char* ldsB = base + 16384 + (wcol * 64 + c) * 64;
    s16x8 a[4], b[4];
#pragma unroll
    for (int mi = 0; mi < 4; ++mi) a[mi] = *(const s16x8*)(ldsA + mi * 1024 + aoff);
#pragma unroll
    for (int ni = 0; ni < 4; ++ni) b[ni] = *(const s16x8*)(ldsB + ni * 1024 + aoff);
    asm volatile("s_waitcnt lgkmcnt(0)" ::: "memory");  // my reads of buf[i&1] done
    __builtin_amdgcn_sched_barrier(0);
    __builtin_amdgcn_s_barrier();                       // all waves done with buf[i&1]
    __builtin_amdgcn_sched_barrier(0);
    if (i + 2 < NT) STAGE(i + 2, i & 1);                // refill now-free buffer
    __builtin_amdgcn_s_setprio(1);
#pragma unroll
    for (int mi = 0; mi < 4; ++mi)
#pragma unroll
      for (int ni = 0; ni < 4; ++ni)
        acc[mi][ni] = mfma32(a[mi], b[ni], acc[mi][ni]);
    __builtin_amdgcn_s_setprio(0);
    if (i < NT - 2) {
      asm volatile("s_waitcnt vmcnt(2)" ::: "memory");  // tile i+1 ready (i+2 in flight)
      __builtin_amdgcn_s_barrier();
      __builtin_amdgcn_sched_barrier(0);
    } else if (i == NT - 2) {
      asm volatile("s_waitcnt vmcnt(0)" ::: "memory");
      __builtin_amdgcn_s_barrier();
      __builtin_amdgcn_sched_barrier(0);
    }
  }

  if (MODE != 4) {
#pragma unroll
    for (int mi = 0; mi < 4; ++mi) {
#pragma unroll
      for (int ni = 0; ni < 4; ++ni) {
        int col = n0 + wcol * 64 + ni * 16 + c;
        float bv = bias ? bias[col] : 0.0f;
#pragma unroll
        for (int jj = 0; jj < 4; ++jj) {
          int row = m0 + wrow * 64 + mi * 16 + g * 4 + jj;
          float val = acc[mi][ni][jj] + bv;
          size_t oi = (size_t)row * N + col;
          if (MODE == 1) val = fmaxf(val, 0.0f);
          else if (MODE == 2) { ((float*)outp)[oi] = resid[oi] + val; continue; }
          if (MODE == 3) ((float*)outp)[oi] = val;
          else           ((bfu*)outp)[oi] = f2bf(val);
        }
      }
    }
  } else {
    // MODE 4: fp32 logits + per-(row, colblock) logsumexp partials (two-phase reduce)
    float* sred = (float*)(smem + 65536);  // [16 waves][64 rows][2] = 8KB
    const int ncb = N >> 8;
    float bvv[4]; int colv[4];
#pragma unroll
    for (int ni = 0; ni < 4; ++ni) {
      colv[ni] = n0 + wcol * 64 + ni * 16 + c;
      bvv[ni] = bias ? bias[colv[ni]] : 0.0f;
    }
#pragma unroll
    for (int mi = 0; mi < 4; ++mi) {
#pragma unroll
      for (int jj = 0; jj < 4; ++jj) {
        int row = m0 + wrow * 64 + mi * 16 + g * 4 + jj;
        float v[4];
#pragma unroll
        for (int ni = 0; ni < 4; ++ni) {
          v[ni] = acc[mi][ni][jj] + bvv[ni];
          ((float*)outp)[(size_t)row * N + colv[ni]] = v[ni];
        }
        float mx = fmaxf(fmaxf(v[0], v[1]), fmaxf(v[2], v[3]));
#pragma unroll
        for (int off = 1; off < 16; off <<= 1) mx = fmaxf(mx, __shfl_xor(mx, off));
        float sm = __expf(v[0] - mx) + __expf(v[1] - mx) +
                   __expf(v[2] - mx) + __expf(v[3] - mx);
#pragma unroll
        for (int off = 1; off < 16; off <<= 1) sm += __shfl_xor(sm, off);
        if (c == 0) {
          int r64 = mi * 16 + g * 4 + jj;
          sred[(w * 64 + r64) * 2 + 0] = mx;
          sred[(w * 64 + r64) * 2 + 1] = sm;
        }
      }
    }
    __syncthreads();
    if (tid < 256) {
      int wr = tid >> 6, r64 = tid & 63;
      float M2 = -3.0e38f, S2 = 0.0f;
#pragma unroll
      for (int wc2 = 0; wc2 < 4; ++wc2) {
        float m_i = sred[((wr * 4 + wc2) * 64 + r64) * 2 + 0];
        float s_i = sred[((wr * 4 + wc2) * 64 + r64) * 2 + 1];
        float nm = fmaxf(M2, m_i);
        S2 = S2 * __expf(M2 - nm) + s_i * __expf(m_i - nm);
        M2 = nm;
      }
      size_t pi = (size_t)(m0 + tid) * ncb + bx;
      pmax[pi] = M2;
      psum[pi] = S2;
    }
  }
}

// ---------------- flash attention v8: QBLK=128, 8 waves/block, single-pass staging ----------
__global__ __launch_bounds__(512) void attn_kernel(const bfu* __restrict__ qkv,
                                                   const bfu* __restrict__ vT,
                                                   bfu* __restrict__ o) {
  __shared__ __align__(16) bfu Ks[64 * 64];        // [key r][d], granule j at j^(r&7)
  __shared__ __align__(16) bfu Vt[64 * 64];        // [d][t],   granule j at j^(d&7)
  __shared__ __align__(16) bfu Plds[8 * 16 * 32];  // per-wave P slots
  const int tid = threadIdx.x;
  const int lane = tid & 63, w = tid >> 6;         // 8 waves
  const int c = lane & 15, g = lane >> 4;
  const int qt = blockIdx.x, hh = blockIdx.y, b = blockIdx.z;
  const int q0 = qt * 128 + w * 16;
  const float SENT = -1e30f;
  const size_t rowb = (size_t)b * SEQ;

  const size_t qbase = (rowb + q0 + c) * QKVS + hh * HEADD + g * 8;
  s16x8 qf0 = *(const s16x8*)&qkv[qbase];
  s16x8 qf1 = *(const s16x8*)&qkv[qbase + 32];
  const bfu* Kg = qkv + 1024 + hh * HEADD;
  const bfu* vTb = vT + (size_t)(b * NH + hh) * HEADD * SEQ;
  bfu* Pw = Plds + w * 512;

  const int srow = tid >> 3;
  const int sgr = (tid & 7) ^ (srow & 7);
  const int cw = c & 7;

  f32x4 oacc[4] = {};
  float mrun = SENT, lrun = 0.0f;

  const int nkt = 2 * qt + 2;
  for (int kt = 0; kt < nkt; ++kt) {
    const int k0 = kt * 64;
    __syncthreads();
    gload16(Kg + (rowb + k0 + srow) * QKVS + sgr * 8, (char*)Ks + w * 1024);
    gload16(vTb + (size_t)srow * SEQ + k0 + sgr * 8, (char*)Vt + w * 1024);
    asm volatile("s_waitcnt vmcnt(0)" ::: "memory");
    __syncthreads();

#pragma unroll
    for (int s = 0; s < 2; ++s) {
      const int k0s = k0 + s * 32;
      if (k0s <= q0 + 15) {
        const char* Kb = (const char*)Ks + (size_t)(s * 32 + c) * 128;
        s16x8 kf00 = *(const s16x8*)(Kb + ((g ^ cw) * 16));
        s16x8 kf01 = *(const s16x8*)(Kb + (((4 + g) ^ cw) * 16));
        s16x8 kf10 = *(const s16x8*)(Kb + 16 * 128 + ((g ^ cw) * 16));
        s16x8 kf11 = *(const s16x8*)(Kb + 16 * 128 + (((4 + g) ^ cw) * 16));
        f32x4 s0 = {}, s1 = {};
        s0 = mfma32(kf00, qf0, s0); s0 = mfma32(kf01, qf1, s0);
        s1 = mfma32(kf10, qf0, s1); s1 = mfma32(kf11, qf1, s1);

        float sv[8];
#pragma unroll
        for (int jj = 0; jj < 4; ++jj) {
          int ka = k0s + g * 4 + jj, kb = ka + 16;
          sv[jj]     = (ka <= q0 + c) ? s0[jj] * 0.125f : SENT;
          sv[4 + jj] = (kb <= q0 + c) ? s1[jj] * 0.125f : SENT;
        }
        float tmax = sv[0];
#pragma unroll
        for (int i = 1; i < 8; ++i) tmax = fmaxf(tmax, sv[i]);
        tmax = fmaxf(tmax, __shfl_xor(tmax, 16));
        tmax = fmaxf(tmax, __shfl_xor(tmax, 32));

        bool defer = __all(tmax <= mrun + 8.0f) && (kt | s);
        float mref = defer ? mrun : fmaxf(mrun, tmax);
        float p[8], psm = 0.0f;
#pragma unroll
        for (int i = 0; i < 8; ++i) { p[i] = __expf(sv[i] - mref); psm += p[i]; }
        psm += __shfl_xor(psm, 16);
        psm += __shfl_xor(psm, 32);

        ushort4 w0; w0.x = f2bf(p[0]); w0.y = f2bf(p[1]); w0.z = f2bf(p[2]); w0.w = f2bf(p[3]);
        ushort4 w1; w1.x = f2bf(p[4]); w1.y = f2bf(p[5]); w1.z = f2bf(p[6]); w1.w = f2bf(p[7]);
        *(ushort4*)&Pw[c * 32 + g * 4] = w0;
        *(ushort4*)&Pw[c * 32 + 16 + g * 4] = w1;
        asm volatile("s_waitcnt lgkmcnt(0)" ::: "memory");
        __builtin_amdgcn_sched_barrier(0);

        if (defer) {
          lrun += psm;
        } else {
          float mnew = mref;
          float alpha = __expf(mrun - mnew);
          lrun = lrun * alpha + psm;
          mrun = mnew;
          float aq[4];
#pragma unroll
          for (int jj = 0; jj < 4; ++jj) aq[jj] = __shfl(alpha, g * 4 + jj);
#pragma unroll
          for (int dg = 0; dg < 4; ++dg)
#pragma unroll
            for (int jj = 0; jj < 4; ++jj) oacc[dg][jj] *= aq[jj];
        }

        ushort4 ra = *(const ushort4*)&Pw[c * 32 + g * 8];
        ushort4 rb = *(const ushort4*)&Pw[c * 32 + g * 8 + 4];
        s16x8 pa = {(short)ra.x, (short)ra.y, (short)ra.z, (short)ra.w,
                    (short)rb.x, (short)rb.y, (short)rb.z, (short)rb.w};

#pragma unroll
        for (int dg = 0; dg < 4; ++dg) {
          s16x8 vf = *(const s16x8*)((const char*)Vt + (size_t)(dg * 16 + c) * 128 +
                                     (((s * 4 + g) ^ cw) * 16));
          oacc[dg] = mfma32(pa, vf, oacc[dg]);
        }
      }
    }
  }

  float lq[4];
#pragma unroll
  for (int jj = 0; jj < 4; ++jj) lq[jj] = __shfl(lrun, g * 4 + jj);
#pragma unroll
  for (int dg = 0; dg < 4; ++dg)
#pragma unroll
    for (int jj = 0; jj < 4; ++jj) {
      size_t oi = (size_t)(rowb + q0 + g * 4 + jj) * DIM + hh * HEADD + dg * 16 + c;
      o[oi] = f2bf(oacc[dg][jj] / lq[jj]);
    }
}

// ---------------- NLL finish ----------------
__global__ __launch_bounds__(64) void nll_finish(const float* __restrict__ pmax,
                                                 const float* __restrict__ psum,
                                                 const float* __restrict__ logits,
                                                 const int* __restrict__ tgt,
                                                 float* __restrict__ nll) {
  int row = blockIdx.x, lane = threadIdx.x;
  const float* pm = pmax + (size_t)row * NCB;
  const float* ps = psum + (size_t)row * NCB;
  float m = -3.0e38f, s = 0.0f;
  if (lane < NCB) { m = pm[lane]; s = ps[lane]; }
  int i2 = lane + 64;
  if (i2 < NCB) {
    float m2 = pm[i2], s2 = ps[i2];
    float nm = fmaxf(m, m2);
    s = s * __expf(m - nm) + s2 * __expf(m2 - nm);
    m = nm;
  }
#pragma unroll
  for (int off = 32; off; off >>= 1) {
    float om = __shfl_xor(m, off), os = __shfl_xor(s, off);
    float nm = fmaxf(m, om);
    s = s * __expf(m - nm) + os * __expf(om - nm);
    m = nm;
  }
  if (lane == 0)
    nll[row] = (m + __logf(s)) - logits[(size_t)row * VOCAB + tgt[row]];
}

__global__ __launch_bounds__(256) void loss_kernel(const float* __restrict__ nll,
                                                   float* __restrict__ out) {
  float s = 0.0f;
  for (int i = threadIdx.x; i < NROW; i += 256) s += nll[i];
  for (int off = 32; off; off >>= 1) s += __shfl_xor(s, off);
  __shared__ float r[4];
  int wave = threadIdx.x >> 6;
  if ((threadIdx.x & 63) == 0) r[wave] = s;
  __syncthreads();
  if (threadIdx.x == 0) out[(size_t)NROW * VOCAB] = (r[0] + r[1] + r[2] + r[3]) * (1.0f / NROW);
}

// ---------------- host ----------------
extern "C" void kernel_launch(void* const* d_in, const int* in_sizes, int n_in,
                              void* d_out, int out_size, void* d_ws, size_t ws_size,
                              hipStream_t stream) {
  (void)in_sizes; (void)n_in; (void)out_size;
  const int* idx       = (const int*)d_in[0];
  const int* targets   = (const int*)d_in[1];
  const float* tok_emb = (const float*)d_in[2];
  const float* pos_emb = (const float*)d_in[3];
  const float* wq      = (const float*)d_in[4];
  const float* wk      = (const float*)d_in[5];
  const float* wv      = (const float*)d_in[6];
  const float* w_proj  = (const float*)d_in[7];
  const float* b_proj  = (const float*)d_in[8];
  const float* w_fc1   = (const float*)d_in[9];
  const float* b_fc1   = (const float*)d_in[10];
  const float* w_fc2   = (const float*)d_in[11];
  const float* b_fc2   = (const float*)d_in[12];
  const float* ln1_g   = (const float*)d_in[13];
  const float* ln1_b   = (const float*)d_in[14];
  const float* ln2_g   = (const float*)d_in[15];
  const float* ln2_b   = (const float*)d_in[16];
  const float* lnf_g   = (const float*)d_in[17];
  const float* lnf_b   = (const float*)d_in[18];
  const float* w_head  = (const float*)d_in[19];
  const float* b_head  = (const float*)d_in[20];

  char* ws = (char*)d_ws;
  size_t off = 0;
  auto alloc = [&](size_t bytes) {
    char* p = ws + off;
    off += (bytes + 255) & ~(size_t)255;
    return p;
  };
  float* xf   = (float*)alloc((size_t)NROW * DIM * 4);
  bfu* hbuf   = (bfu*)alloc((size_t)NROW * DIM * 2);
  bfu* qkvb   = (bfu*)alloc((size_t)NROW * QKVS * 2);
  bfu* ob     = (bfu*)alloc((size_t)NROW * DIM * 2);
  bfu* ub     = (bfu*)alloc((size_t)NROW * FF * 2);
  bfu* vT     = (bfu*)alloc((size_t)NROW * DIM * 2);
  float* pbuf = (float*)alloc((size_t)2 * NROW * DIM * 4);   // fc2 K-split partials
  bfu* qkvT   = (bfu*)alloc((size_t)QKVS * DIM * 2);
  bfu* wpT    = (bfu*)alloc((size_t)DIM * DIM * 2);
  bfu* f1T    = (bfu*)alloc((size_t)DIM * FF * 2);
  bfu* f2T    = (bfu*)alloc((size_t)DIM * FF * 2);
  bfu* hT     = (bfu*)alloc((size_t)DIM * VOCAB * 2);
  float* nll  = (float*)alloc((size_t)NROW * 4);
  float* pmax = (float*)alloc((size_t)NROW * NCB * 4);
  float* psum = (float*)alloc((size_t)NROW * NCB * 4);
  if (off > ws_size) return;

  const size_t LDSB = 65536;   // gemm1024 BK32: 2 x (A 16K + B 16K)
  dim3 tb(32, 8);
  tkernel<<<dim3(VOCAB / 32, DIM / 32), tb, 0, stream>>>(w_head, hT, DIM, VOCAB);
  embed_kernel<<<NROW, 256, 0, stream>>>(idx, tok_emb, pos_emb, xf);

  float* logits = (float*)d_out;
  for (int l = 0; l < LAYERS; ++l) {
    const size_t wo = (size_t)l * DIM * DIM, fo = (size_t)l * DIM * FF;
    wtrans_kernel<<<12288, tb, 0, stream>>>(wq + wo, wk + wo, wv + wo, w_proj + wo,
                                            w_fc1 + fo, w_fc2 + fo, qkvT, wpT, f1T, f2T);
    if (l == 0)
      ln_kernel<<<NROW / 4, 256, 0, stream>>>(xf, ln1_g, ln1_b, hbuf);
    else
      lnfuse_kernel<<<NROW / 4, 256, 0, stream>>>(xf, pbuf, b_fc2 + (l - 1) * DIM,
                                                  ln1_g + l * DIM, ln1_b + l * DIM, hbuf);
    gemm_bt<5><<<dim3(QKVS / 128, NROW / 128), 256, 0, stream>>>(
        hbuf, qkvT, nullptr, nullptr, qkvb, vT, NROW, QKVS, DIM, DIM);
    attn_kernel<<<dim3(SEQ / 128, NH, NBATCH), 512, 0, stream>>>(qkvb, vT, ob);
    gemm_bt<2><<<dim3(DIM / 128, NROW / 128), 256, 0, stream>>>(
        ob, wpT, b_proj + l * DIM, xf, xf, nullptr, NROW, DIM, DIM, DIM);
    ln_kernel<<<NROW / 4, 256, 0, stream>>>(xf, ln2_g + l * DIM, ln2_b + l * DIM, hbuf);
    gemm1024<1><<<dim3(FF / 256, NROW / 256), 1024, LDSB, stream>>>(
        hbuf, f1T, b_fc1 + l * FF, nullptr, ub, NROW, FF, DIM, 0, nullptr, nullptr);
    gemm_bt<6><<<dim3(DIM / 128, NROW / 128, 2), 256, 0, stream>>>(
        ub, f2T, nullptr, nullptr, pbuf, nullptr, NROW, DIM, FF / 2, FF);
  }

  lnfuse_kernel<<<NROW / 4, 256, 0, stream>>>(xf, pbuf, b_fc2 + 5 * DIM, lnf_g, lnf_b, hbuf);
  gemm1024<4><<<dim3(VOCAB / 256, NROW / 256), 1024, LDSB + 8192, stream>>>(
      hbuf, hT, b_head, nullptr, logits, NROW, VOCAB, DIM, 1, pmax, psum);
  nll_finish<<<NROW, 64, 0, stream>>>(pmax, psum, logits, targets, nll);
  loss_kernel<<<1, 256, 0, stream>>>(nll, logits);
}

// Round 18
// 1960.103 us; speedup vs baseline: 1.1010x; 1.1010x over previous
//
#include <hip/hip_runtime.h>

#define LAYERS 6
#define NH 16
#define DIM 1024
#define VOCAB 32000
#define SEQ 2048
#define NBATCH 2
#define HEADD 64
#define NROW (NBATCH*SEQ)   // 4096
#define FF 4096
#define QKVS 3072
#define NCB (VOCAB/256)     // 125 col-blocks in head GEMM
#define LN_EPS 1e-5f

typedef unsigned short bfu;  // bf16 bits
typedef __attribute__((ext_vector_type(8))) short s16x8;
typedef __attribute__((ext_vector_type(4))) float f32x4;

__device__ __forceinline__ float bf2f(bfu u) { return __uint_as_float(((unsigned)u) << 16); }
__device__ __forceinline__ bfu f2bf(float x) {
  unsigned u = __float_as_uint(x);
  return (bfu)((u + 0x7fffu + ((u >> 16) & 1u)) >> 16);  // RNE
}

__device__ __forceinline__ void gload16(const void* g, void* l) {
  __builtin_amdgcn_global_load_lds((const __attribute__((address_space(1))) void*)g,
                                   (__attribute__((address_space(3))) void*)l, 16, 0, 0);
}

__device__ __forceinline__ f32x4 mfma32(s16x8 a, s16x8 b, f32x4 c) {
  return __builtin_amdgcn_mfma_f32_16x16x32_bf16(a, b, c, 0, 0, 0);
}

// ---------------- transpose+convert: out[C][R] (bf16) = in[R][C]^T (fp32) ----------------
__global__ __launch_bounds__(256) void tkernel(const float* __restrict__ in,
                                               bfu* __restrict__ out, int R, int C) {
  __shared__ bfu tile[32][33];
  int tx = threadIdx.x, ty = threadIdx.y;
  int bx = blockIdx.x * 32, by = blockIdx.y * 32;
#pragma unroll
  for (int i = 0; i < 4; ++i)
    tile[ty + i * 8][tx] = f2bf(in[(size_t)(by + ty + i * 8) * C + bx + tx]);
  __syncthreads();
#pragma unroll
  for (int i = 0; i < 4; ++i)
    out[(size_t)(bx + ty + i * 8) * R + by + tx] = tile[tx][ty + i * 8];
}

// ---- merged per-layer weight transpose: qkv(3) + proj + fc1 + fc2 in ONE launch ----
__global__ __launch_bounds__(256) void wtrans_kernel(const float* __restrict__ wq,
                                                     const float* __restrict__ wk,
                                                     const float* __restrict__ wv,
                                                     const float* __restrict__ wp,
                                                     const float* __restrict__ w1,
                                                     const float* __restrict__ w2,
                                                     bfu* __restrict__ qkvT,
                                                     bfu* __restrict__ wpT,
                                                     bfu* __restrict__ f1T,
                                                     bfu* __restrict__ f2T) {
  __shared__ bfu tile[32][33];
  int bi = blockIdx.x;
  const float* in; bfu* out; int R, C, id;
  if (bi < 4096) {
    int p = bi >> 10; id = bi & 1023;
    in = p == 0 ? wq : p == 1 ? wk : p == 2 ? wv : wp;
    out = (p == 3) ? wpT : qkvT + (size_t)p * DIM * DIM;
    R = DIM; C = DIM;
  } else if (bi < 8192) {
    id = bi - 4096; in = w1; out = f1T; R = DIM; C = FF;
  } else {
    id = bi - 8192; in = w2; out = f2T; R = FF; C = DIM;
  }
  int nbx = C >> 5;
  int bx = (id % nbx) * 32, by = (id / nbx) * 32;
  int tx = threadIdx.x, ty = threadIdx.y;
#pragma unroll
  for (int i = 0; i < 4; ++i)
    tile[ty + i * 8][tx] = f2bf(in[(size_t)(by + ty + i * 8) * C + bx + tx]);
  __syncthreads();
#pragma unroll
  for (int i = 0; i < 4; ++i)
    out[(size_t)(bx + ty + i * 8) * R + by + tx] = tile[tx][ty + i * 8];
}

// ---------------- embedding ----------------
__global__ __launch_bounds__(256) void embed_kernel(const int* __restrict__ idx,
                                                    const float* __restrict__ tok,
                                                    const float* __restrict__ pos,
                                                    float* __restrict__ xf) {
  int row = blockIdx.x;
  int t = row % SEQ;
  int tokid = idx[row];
  int d0 = threadIdx.x * 4;
  float4 tv = *(const float4*)&tok[(size_t)tokid * DIM + d0];
  float4 pv = *(const float4*)&pos[(size_t)t * DIM + d0];
  float4 r;
  r.x = tv.x + pv.x; r.y = tv.y + pv.y; r.z = tv.z + pv.z; r.w = tv.w + pv.w;
  *(float4*)&xf[(size_t)row * DIM + d0] = r;
}

// ---------------- LayerNorm v2: one wave per row (no barriers, no LDS) ----------------
__global__ __launch_bounds__(256) void ln_kernel(const float* __restrict__ xf,
                                                 const float* __restrict__ gw,
                                                 const float* __restrict__ bw,
                                                 bfu* __restrict__ h) {
  const int row = blockIdx.x * 4 + (threadIdx.x >> 6);
  const int lane = threadIdx.x & 63;
  const float* xr = xf + (size_t)row * DIM;
  float4 xv[4];
  float s = 0.0f, ss = 0.0f;
#pragma unroll
  for (int j = 0; j < 4; ++j) {
    xv[j] = *(const float4*)&xr[lane * 4 + j * 256];
    s  += xv[j].x + xv[j].y + xv[j].z + xv[j].w;
    ss += xv[j].x * xv[j].x + xv[j].y * xv[j].y + xv[j].z * xv[j].z + xv[j].w * xv[j].w;
  }
#pragma unroll
  for (int o = 32; o; o >>= 1) { s += __shfl_xor(s, o); ss += __shfl_xor(ss, o); }
  float mean = s * (1.0f / DIM);
  float inv = rsqrtf(ss * (1.0f / DIM) - mean * mean + LN_EPS);
#pragma unroll
  for (int j = 0; j < 4; ++j) {
    float4 gv = *(const float4*)&gw[lane * 4 + j * 256];
    float4 bv = *(const float4*)&bw[lane * 4 + j * 256];
    ushort4 hv;
    hv.x = f2bf((xv[j].x - mean) * inv * gv.x + bv.x);
    hv.y = f2bf((xv[j].y - mean) * inv * gv.y + bv.y);
    hv.z = f2bf((xv[j].z - mean) * inv * gv.z + bv.z);
    hv.w = f2bf((xv[j].w - mean) * inv * gv.w + bv.w);
    *(ushort4*)&h[(size_t)row * DIM + lane * 4 + j * 256] = hv;
  }
}

// ---- LN with fused partial combine: x = xf + p0 + p1 + bias; xf = x; h = LN(x) ----
__global__ __launch_bounds__(256) void lnfuse_kernel(float* __restrict__ xf,
                                                     const float* __restrict__ pb,
                                                     const float* __restrict__ bias,
                                                     const float* __restrict__ gw,
                                                     const float* __restrict__ bw,
                                                     bfu* __restrict__ h) {
  const int row = blockIdx.x * 4 + (threadIdx.x >> 6);
  const int lane = threadIdx.x & 63;
  float* xr = xf + (size_t)row * DIM;
  const float* p0 = pb + (size_t)row * DIM;
  const float* p1 = pb + (size_t)NROW * DIM + (size_t)row * DIM;
  float4 xv[4];
  float s = 0.0f, ss = 0.0f;
#pragma unroll
  for (int j = 0; j < 4; ++j) {
    int i0 = lane * 4 + j * 256;
    float4 a = *(const float4*)&xr[i0];
    float4 q0 = *(const float4*)&p0[i0];
    float4 q1 = *(const float4*)&p1[i0];
    float4 bb = *(const float4*)&bias[i0];
    xv[j].x = a.x + q0.x + q1.x + bb.x;
    xv[j].y = a.y + q0.y + q1.y + bb.y;
    xv[j].z = a.z + q0.z + q1.z + bb.z;
    xv[j].w = a.w + q0.w + q1.w + bb.w;
    *(float4*)&xr[i0] = xv[j];
    s  += xv[j].x + xv[j].y + xv[j].z + xv[j].w;
    ss += xv[j].x * xv[j].x + xv[j].y * xv[j].y + xv[j].z * xv[j].z + xv[j].w * xv[j].w;
  }
#pragma unroll
  for (int o = 32; o; o >>= 1) { s += __shfl_xor(s, o); ss += __shfl_xor(ss, o); }
  float mean = s * (1.0f / DIM);
  float inv = rsqrtf(ss * (1.0f / DIM) - mean * mean + LN_EPS);
#pragma unroll
  for (int j = 0; j < 4; ++j) {
    int i0 = lane * 4 + j * 256;
    float4 gv = *(const float4*)&gw[i0];
    float4 bv = *(const float4*)&bw[i0];
    ushort4 hv;
    hv.x = f2bf((xv[j].x - mean) * inv * gv.x + bv.x);
    hv.y = f2bf((xv[j].y - mean) * inv * gv.y + bv.y);
    hv.z = f2bf((xv[j].z - mean) * inv * gv.z + bv.z);
    hv.w = f2bf((xv[j].w - mean) * inv * gv.w + bv.w);
    *(ushort4*)&h[(size_t)row * DIM + i0] = hv;
  }
}

// ---------------- GEMM 128x128xBK32, ring-2 counted-vmcnt ----------------
// MODE 0: bf16 = acc(+bias); 1: bf16 relu; 2: fp32 = resid+acc+bias;
// MODE 5: bf16 = acc, + fused V-transpose write for cols>=2048 (qkv);
// MODE 6: fp32 partial plane bz (K-split via gridDim.z; no bias/resid).
template <int MODE>
__global__ __launch_bounds__(256) void gemm_bt(const bfu* __restrict__ A,
                                               const bfu* __restrict__ Bt,
                                               const float* __restrict__ bias,
                                               const float* resid,
                                               void* outp,
                                               bfu* __restrict__ vT,
                                               int M, int N, int K, int ldk) {
  __shared__ __align__(16) char sm[32768];  // 2 bufs x (A 8K | B 8K)
  const int tid = threadIdx.x;
  const int lane = tid & 63, wave = tid >> 6;
  const int c = lane & 15, g = lane >> 4;

  const int gx = gridDim.x, gy = gridDim.y, gz = gridDim.z;
  int orig = (blockIdx.z * gy + blockIdx.y) * gx + blockIdx.x;   // dispatch order
  int nwg = gx * gy * gz;
  int cpx = nwg >> 3;
  int swz = (orig & 7) * cpx + (orig >> 3);
  int bz = swz / (gx * gy);
  int rem = swz - bz * (gx * gy);
  int by = rem / gx, bx = rem - by * gx;

  const int m0 = by * 128, n0 = bx * 128;
  const int wm = (wave & 1) * 64, wn = (wave >> 1) * 64;
  f32x4 acc[4][4] = {};
  const char* Ac = (const char*)(A + (size_t)bz * K);  // K-split offset (elements)
  const char* Bc = (const char*)(Bt + (size_t)bz * K);
  const size_t stride = (size_t)ldk * 2;

  const int g1 = tid, g2 = tid + 256;
  const int r1 = g1 >> 2, j1 = g1 & 3;
  const int r2 = g2 >> 2, j2 = g2 & 3;
  const size_t a1 = (size_t)(m0 + r1) * stride + j1 * 16;
  const size_t a2 = (size_t)(m0 + r2) * stride + j2 * 16;
  const size_t b1 = (size_t)(n0 + r1) * stride + j1 * 16;
  const size_t b2 = (size_t)(n0 + r2) * stride + j2 * 16;

  auto STAGE = [&](int kt, int buf) {
    char* base = sm + buf * 16384;
    size_t ko = (size_t)kt * 64;
    gload16(Ac + a1 + ko, base + g1 * 16);
    gload16(Ac + a2 + ko, base + g2 * 16);
    gload16(Bc + b1 + ko, base + 8192 + g1 * 16);
    gload16(Bc + b2 + ko, base + 8192 + g2 * 16);
  };

  const int NT = K >> 5;
  STAGE(0, 0);
  STAGE(1, 1);
  asm volatile("s_waitcnt vmcnt(4)" ::: "memory");
  __builtin_amdgcn_s_barrier();
  __builtin_amdgcn_sched_barrier(0);

  for (int i = 0; i < NT; ++i) {
    const char* base = sm + (i & 1) * 16384;
    s16x8 af[4], bfr[4];
#pragma unroll
    for (int mi = 0; mi < 4; ++mi)
      af[mi] = *(const s16x8*)(base + (wm + mi * 16 + c) * 64 + g * 16);
#pragma unroll
    for (int ni = 0; ni < 4; ++ni)
      bfr[ni] = *(const s16x8*)(base + 8192 + (wn + ni * 16 + c) * 64 + g * 16);
    asm volatile("s_waitcnt lgkmcnt(0)" ::: "memory");
    __builtin_amdgcn_sched_barrier(0);
    __builtin_amdgcn_s_barrier();
    __builtin_amdgcn_sched_barrier(0);
    if (i + 2 < NT) STAGE(i + 2, i & 1);
    __builtin_amdgcn_s_setprio(1);
#pragma unroll
    for (int mi = 0; mi < 4; ++mi)
#pragma unroll
      for (int ni = 0; ni < 4; ++ni)
        acc[mi][ni] = mfma32(af[mi], bfr[ni], acc[mi][ni]);
    __builtin_amdgcn_s_setprio(0);
    if (i < NT - 2) {
      asm volatile("s_waitcnt vmcnt(4)" ::: "memory");
      __builtin_amdgcn_s_barrier();
      __builtin_amdgcn_sched_barrier(0);
    } else if (i == NT - 2) {
      asm volatile("s_waitcnt vmcnt(0)" ::: "memory");
      __builtin_amdgcn_s_barrier();
      __builtin_amdgcn_sched_barrier(0);
    }
  }

#pragma unroll
  for (int mi = 0; mi < 4; ++mi) {
#pragma unroll
    for (int ni = 0; ni < 4; ++ni) {
      int col = n0 + wn + ni * 16 + c;
      float bv = (MODE != 6 && bias) ? bias[col] : 0.0f;
#pragma unroll
      for (int jj = 0; jj < 4; ++jj) {
        int row = m0 + wm + mi * 16 + g * 4 + jj;
        float val = acc[mi][ni][jj] + bv;
        size_t oi = (size_t)row * N + col;
        if (MODE == 1) val = fmaxf(val, 0.0f);
        if (MODE == 2)      ((float*)outp)[oi] = resid[oi] + val;
        else if (MODE == 6) ((float*)outp)[(size_t)bz * M * N + oi] = val;
        else {
          ((bfu*)outp)[oi] = f2bf(val);
          if (MODE == 5 && col >= 2048) {    // fused V transpose: vT[(b,h,d)][t]
            int d = col - 2048;
            int b2 = row >> 11, t = row & 2047;
            vT[((size_t)((b2 << 4) + (d >> 6)) * HEADD + (d & 63)) * SEQ + t] = f2bf(val);
          }
        }
      }
    }
  }
}

// ---------------- GEMM 256x256xBK64, 16 waves (64x64/wave), ring-2 counted-vmcnt ----------------
// (round-16 proven config: BK64, 128KB LDS; BK32 variant caused 8-way LDS bank conflicts)
// MODE 1: bf16 relu(acc+bias); MODE 3: fp32 acc+bias; MODE 4: MODE 3 + logsumexp partials
template <int MODE>
__global__ __launch_bounds__(1024) void gemm1024(const bfu* __restrict__ A,
                                                 const bfu* __restrict__ Bt,
                                                 const float* __restrict__ bias,
                                                 const float* resid,
                                                 void* outp,
                                                 int M, int N, int K,
                                                 int colchunk,
                                                 float* __restrict__ pmax,
                                                 float* __restrict__ psum) {
  extern __shared__ char smem[];
  const int tid = threadIdx.x;
  const int lane = tid & 63, w = tid >> 6;
  const int c = lane & 15, g = lane >> 4;

  const int gx = gridDim.x, gy = gridDim.y;
  int orig = blockIdx.y * gx + blockIdx.x;
  int cpx = (gx * gy) >> 3;
  int swz = (orig & 7) * cpx + (orig >> 3);
  int bx, by;
  if (colchunk) { bx = swz / gy; by = swz - bx * gy; }
  else          { by = swz / gx; bx = swz - by * gx; }
  const int m0 = by * 256, n0 = bx * 256;

  const int wrow = w >> 2, wcol = w & 3;
  const size_t gstr = (size_t)K * 2;
  const char* Ag = (const char*)A + (size_t)m0 * gstr;
  const char* Bg = (const char*)Bt + (size_t)n0 * gstr;

  int srow0 = tid >> 3, scg0 = (tid & 7) ^ (srow0 & 7);
  int srow1 = (tid + 1024) >> 3, scg1 = (tid & 7) ^ (srow1 & 7);
  const size_t ga0 = (size_t)srow0 * gstr + scg0 * 16;
  const size_t ga1 = (size_t)srow1 * gstr + scg1 * 16;

  auto STAGE = [&](int kt, int buf) {
    char* base = smem + buf * 65536;
    size_t ko = (size_t)kt * 128;
    gload16(Ag + ga0 + ko, base + w * 1024);
    gload16(Ag + ga1 + ko, base + 16384 + w * 1024);
    gload16(Bg + ga0 + ko, base + 32768 + w * 1024);
    gload16(Bg + ga1 + ko, base + 49152 + w * 1024);
  };

  const int NT = K >> 6;
  f32x4 acc[4][4] = {};

  STAGE(0, 0);
  STAGE(1, 1);
  asm volatile("s_waitcnt vmcnt(4)" ::: "memory");
  __builtin_amdgcn_s_barrier();
  __builtin_amdgcn_sched_barrier(0);

  const int rsw = (c & 7) << 4;
  const int off0 = (g * 16) ^ rsw;
  const int off1 = (64 + g * 16) ^ rsw;

  for (int i = 0; i < NT; ++i) {
    const char* ldsA = smem + (i & 1) * 65536 + (wrow * 64 + c) * 128;
    const char* ldsB = smem + (i & 1) * 65536 + 32768 + (wcol * 64 + c) * 128;
    s16x8 a[4], b[4];
#pragma unroll
    for (int mi = 0; mi < 4; ++mi) a[mi] = *(const s16x8*)(ldsA + mi * 2048 + off0);
#pragma unroll
    for (int ni = 0; ni < 4; ++ni) b[ni] = *(const s16x8*)(ldsB + ni * 2048 + off0);
    __builtin_amdgcn_s_setprio(1);
#pragma unroll
    for (int mi = 0; mi < 4; ++mi)
#pragma unroll
      for (int ni = 0; ni < 4; ++ni)
        acc[mi][ni] = mfma32(a[mi], b[ni], acc[mi][ni]);
    __builtin_amdgcn_s_setprio(0);
#pragma unroll
    for (int mi = 0; mi < 4; ++mi) a[mi] = *(const s16x8*)(ldsA + mi * 2048 + off1);
#pragma unroll
    for (int ni = 0; ni < 4; ++ni) b[ni] = *(const s16x8*)(ldsB + ni * 2048 + off1);
    asm volatile("s_waitcnt lgkmcnt(0)" ::: "memory");
    __builtin_amdgcn_sched_barrier(0);
    __builtin_amdgcn_s_barrier();
    __builtin_amdgcn_sched_barrier(0);
    if (i + 2 < NT) STAGE(i + 2, i & 1);
    __builtin_amdgcn_s_setprio(1);
#pragma unroll
    for (int mi = 0; mi < 4; ++mi)
#pragma unroll
      for (int ni = 0; ni < 4; ++ni)
        acc[mi][ni] = mfma32(a[mi], b[ni], acc[mi][ni]);
    __builtin_amdgcn_s_setprio(0);
    if (i < NT - 2) {
      asm volatile("s_waitcnt vmcnt(4)" ::: "memory");
      __builtin_amdgcn_s_barrier();
      __builtin_amdgcn_sched_barrier(0);
    } else if (i == NT - 2) {
      asm volatile("s_waitcnt vmcnt(0)" ::: "memory");
      __builtin_amdgcn_s_barrier();
      __builtin_amdgcn_sched_barrier(0);
    }
  }

  if (MODE != 4) {
#pragma unroll
    for (int mi = 0; mi < 4; ++mi) {
#pragma unroll
      for (int ni = 0; ni < 4; ++ni) {
        int col = n0 + wcol * 64 + ni * 16 + c;
        float bv = bias ? bias[col] : 0.0f;
#pragma unroll
        for (int jj = 0; jj < 4; ++jj) {
          int row = m0 + wrow * 64 + mi * 16 + g * 4 + jj;
          float val = acc[mi][ni][jj] + bv;
          size_t oi = (size_t)row * N + col;
          if (MODE == 1) val = fmaxf(val, 0.0f);
          else if (MODE == 2) { ((float*)outp)[oi] = resid[oi] + val; continue; }
          if (MODE == 3) ((float*)outp)[oi] = val;
          else           ((bfu*)outp)[oi] = f2bf(val);
        }
      }
    }
  } else {
    // MODE 4: fp32 logits + per-(row, colblock) logsumexp partials (two-phase reduce)
    float* sred = (float*)(smem + 131072);  // [16 waves][64 rows][2]
    const int ncb = N >> 8;
    float bvv[4]; int colv[4];
#pragma unroll
    for (int ni = 0; ni < 4; ++ni) {
      colv[ni] = n0 + wcol * 64 + ni * 16 + c;
      bvv[ni] = bias ? bias[colv[ni]] : 0.0f;
    }
#pragma unroll
    for (int mi = 0; mi < 4; ++mi) {
#pragma unroll
      for (int jj = 0; jj < 4; ++jj) {
        int row = m0 + wrow * 64 + mi * 16 + g * 4 + jj;
        float v[4];
#pragma unroll
        for (int ni = 0; ni < 4; ++ni) {
          v[ni] = acc[mi][ni][jj] + bvv[ni];
          ((float*)outp)[(size_t)row * N + colv[ni]] = v[ni];
        }
        float mx = fmaxf(fmaxf(v[0], v[1]), fmaxf(v[2], v[3]));
#pragma unroll
        for (int off = 1; off < 16; off <<= 1) mx = fmaxf(mx, __shfl_xor(mx, off));
        float sm = __expf(v[0] - mx) + __expf(v[1] - mx) +
                   __expf(v[2] - mx) + __expf(v[3] - mx);
#pragma unroll
        for (int off = 1; off < 16; off <<= 1) sm += __shfl_xor(sm, off);
        if (c == 0) {
          int r64 = mi * 16 + g * 4 + jj;
          sred[(w * 64 + r64) * 2 + 0] = mx;
          sred[(w * 64 + r64) * 2 + 1] = sm;
        }
      }
    }
    __syncthreads();
    if (tid < 256) {
      int wr = tid >> 6, r64 = tid & 63;
      float M2 = -3.0e38f, S2 = 0.0f;
#pragma unroll
      for (int wc2 = 0; wc2 < 4; ++wc2) {
        float m_i = sred[((wr * 4 + wc2) * 64 + r64) * 2 + 0];
        float s_i = sred[((wr * 4 + wc2) * 64 + r64) * 2 + 1];
        float nm = fmaxf(M2, m_i);
        S2 = S2 * __expf(M2 - nm) + s_i * __expf(m_i - nm);
        M2 = nm;
      }
      size_t pi = (size_t)(m0 + tid) * ncb + bx;
      pmax[pi] = M2;
      psum[pi] = S2;
    }
  }
}

// ---------------- flash attention v8: QBLK=128, 8 waves/block, single-pass staging ----------
__global__ __launch_bounds__(512) void attn_kernel(const bfu* __restrict__ qkv,
                                                   const bfu* __restrict__ vT,
                                                   bfu* __restrict__ o) {
  __shared__ __align__(16) bfu Ks[64 * 64];        // [key r][d], granule j at j^(r&7)
  __shared__ __align__(16) bfu Vt[64 * 64];        // [d][t],   granule j at j^(d&7)
  __shared__ __align__(16) bfu Plds[8 * 16 * 32];  // per-wave P slots
  const int tid = threadIdx.x;
  const int lane = tid & 63, w = tid >> 6;         // 8 waves
  const int c = lane & 15, g = lane >> 4;
  const int qt = blockIdx.x, hh = blockIdx.y, b = blockIdx.z;
  const int q0 = qt * 128 + w * 16;
  const float SENT = -1e30f;
  const size_t rowb = (size_t)b * SEQ;

  const size_t qbase = (rowb + q0 + c) * QKVS + hh * HEADD + g * 8;
  s16x8 qf0 = *(const s16x8*)&qkv[qbase];
  s16x8 qf1 = *(const s16x8*)&qkv[qbase + 32];
  const bfu* Kg = qkv + 1024 + hh * HEADD;
  const bfu* vTb = vT + (size_t)(b * NH + hh) * HEADD * SEQ;
  bfu* Pw = Plds + w * 512;

  const int srow = tid >> 3;
  const int sgr = (tid & 7) ^ (srow & 7);
  const int cw = c & 7;

  f32x4 oacc[4] = {};
  float mrun = SENT, lrun = 0.0f;

  const int nkt = 2 * qt + 2;
  for (int kt = 0; kt < nkt; ++kt) {
    const int k0 = kt * 64;
    __syncthreads();
    gload16(Kg + (rowb + k0 + srow) * QKVS + sgr * 8, (char*)Ks + w * 1024);
    gload16(vTb + (size_t)srow * SEQ + k0 + sgr * 8, (char*)Vt + w * 1024);
    asm volatile("s_waitcnt vmcnt(0)" ::: "memory");
    __syncthreads();

#pragma unroll
    for (int s = 0; s < 2; ++s) {
      const int k0s = k0 + s * 32;
      if (k0s <= q0 + 15) {
        const char* Kb = (const char*)Ks + (size_t)(s * 32 + c) * 128;
        s16x8 kf00 = *(const s16x8*)(Kb + ((g ^ cw) * 16));
        s16x8 kf01 = *(const s16x8*)(Kb + (((4 + g) ^ cw) * 16));
        s16x8 kf10 = *(const s16x8*)(Kb + 16 * 128 + ((g ^ cw) * 16));
        s16x8 kf11 = *(const s16x8*)(Kb + 16 * 128 + (((4 + g) ^ cw) * 16));
        f32x4 s0 = {}, s1 = {};
        s0 = mfma32(kf00, qf0, s0); s0 = mfma32(kf01, qf1, s0);
        s1 = mfma32(kf10, qf0, s1); s1 = mfma32(kf11, qf1, s1);

        float sv[8];
#pragma unroll
        for (int jj = 0; jj < 4; ++jj) {
          int ka = k0s + g * 4 + jj, kb = ka + 16;
          sv[jj]     = (ka <= q0 + c) ? s0[jj] * 0.125f : SENT;
          sv[4 + jj] = (kb <= q0 + c) ? s1[jj] * 0.125f : SENT;
        }
        float tmax = sv[0];
#pragma unroll
        for (int i = 1; i < 8; ++i) tmax = fmaxf(tmax, sv[i]);
        tmax = fmaxf(tmax, __shfl_xor(tmax, 16));
        tmax = fmaxf(tmax, __shfl_xor(tmax, 32));

        bool defer = __all(tmax <= mrun + 8.0f) && (kt | s);
        float mref = defer ? mrun : fmaxf(mrun, tmax);
        float p[8], psm = 0.0f;
#pragma unroll
        for (int i = 0; i < 8; ++i) { p[i] = __expf(sv[i] - mref); psm += p[i]; }
        psm += __shfl_xor(psm, 16);
        psm += __shfl_xor(psm, 32);

        ushort4 w0; w0.x = f2bf(p[0]); w0.y = f2bf(p[1]); w0.z = f2bf(p[2]); w0.w = f2bf(p[3]);
        ushort4 w1; w1.x = f2bf(p[4]); w1.y = f2bf(p[5]); w1.z = f2bf(p[6]); w1.w = f2bf(p[7]);
        *(ushort4*)&Pw[c * 32 + g * 4] = w0;
        *(ushort4*)&Pw[c * 32 + 16 + g * 4] = w1;
        asm volatile("s_waitcnt lgkmcnt(0)" ::: "memory");
        __builtin_amdgcn_sched_barrier(0);

        if (defer) {
          lrun += psm;
        } else {
          float mnew = mref;
          float alpha = __expf(mrun - mnew);
          lrun = lrun * alpha + psm;
          mrun = mnew;
          float aq[4];
#pragma unroll
          for (int jj = 0; jj < 4; ++jj) aq[jj] = __shfl(alpha, g * 4 + jj);
#pragma unroll
          for (int dg = 0; dg < 4; ++dg)
#pragma unroll
            for (int jj = 0; jj < 4; ++jj) oacc[dg][jj] *= aq[jj];
        }

        ushort4 ra = *(const ushort4*)&Pw[c * 32 + g * 8];
        ushort4 rb = *(const ushort4*)&Pw[c * 32 + g * 8 + 4];
        s16x8 pa = {(short)ra.x, (short)ra.y, (short)ra.z, (short)ra.w,
                    (short)rb.x, (short)rb.y, (short)rb.z, (short)rb.w};

#pragma unroll
        for (int dg = 0; dg < 4; ++dg) {
          s16x8 vf = *(const s16x8*)((const char*)Vt + (size_t)(dg * 16 + c) * 128 +
                                     (((s * 4 + g) ^ cw) * 16));
          oacc[dg] = mfma32(pa, vf, oacc[dg]);
        }
      }
    }
  }

  float lq[4];
#pragma unroll
  for (int jj = 0; jj < 4; ++jj) lq[jj] = __shfl(lrun, g * 4 + jj);
#pragma unroll
  for (int dg = 0; dg < 4; ++dg)
#pragma unroll
    for (int jj = 0; jj < 4; ++jj) {
      size_t oi = (size_t)(rowb + q0 + g * 4 + jj) * DIM + hh * HEADD + dg * 16 + c;
      o[oi] = f2bf(oacc[dg][jj] / lq[jj]);
    }
}

// ---------------- NLL finish ----------------
__global__ __launch_bounds__(64) void nll_finish(const float* __restrict__ pmax,
                                                 const float* __restrict__ psum,
                                                 const float* __restrict__ logits,
                                                 const int* __restrict__ tgt,
                                                 float* __restrict__ nll) {
  int row = blockIdx.x, lane = threadIdx.x;
  const float* pm = pmax + (size_t)row * NCB;
  const float* ps = psum + (size_t)row * NCB;
  float m = -3.0e38f, s = 0.0f;
  if (lane < NCB) { m = pm[lane]; s = ps[lane]; }
  int i2 = lane + 64;
  if (i2 < NCB) {
    float m2 = pm[i2], s2 = ps[i2];
    float nm = fmaxf(m, m2);
    s = s * __expf(m - nm) + s2 * __expf(m2 - nm);
    m = nm;
  }
#pragma unroll
  for (int off = 32; off; off >>= 1) {
    float om = __shfl_xor(m, off), os = __shfl_xor(s, off);
    float nm = fmaxf(m, om);
    s = s * __expf(m - nm) + os * __expf(om - nm);
    m = nm;
  }
  if (lane == 0)
    nll[row] = (m + __logf(s)) - logits[(size_t)row * VOCAB + tgt[row]];
}

__global__ __launch_bounds__(256) void loss_kernel(const float* __restrict__ nll,
                                                   float* __restrict__ out) {
  float s = 0.0f;
  for (int i = threadIdx.x; i < NROW; i += 256) s += nll[i];
  for (int off = 32; off; off >>= 1) s += __shfl_xor(s, off);
  __shared__ float r[4];
  int wave = threadIdx.x >> 6;
  if ((threadIdx.x & 63) == 0) r[wave] = s;
  __syncthreads();
  if (threadIdx.x == 0) out[(size_t)NROW * VOCAB] = (r[0] + r[1] + r[2] + r[3]) * (1.0f / NROW);
}

// ---------------- host ----------------
extern "C" void kernel_launch(void* const* d_in, const int* in_sizes, int n_in,
                              void* d_out, int out_size, void* d_ws, size_t ws_size,
                              hipStream_t stream) {
  (void)in_sizes; (void)n_in; (void)out_size;
  const int* idx       = (const int*)d_in[0];
  const int* targets   = (const int*)d_in[1];
  const float* tok_emb = (const float*)d_in[2];
  const float* pos_emb = (const float*)d_in[3];
  const float* wq      = (const float*)d_in[4];
  const float* wk      = (const float*)d_in[5];
  const float* wv      = (const float*)d_in[6];
  const float* w_proj  = (const float*)d_in[7];
  const float* b_proj  = (const float*)d_in[8];
  const float* w_fc1   = (const float*)d_in[9];
  const float* b_fc1   = (const float*)d_in[10];
  const float* w_fc2   = (const float*)d_in[11];
  const float* b_fc2   = (const float*)d_in[12];
  const float* ln1_g   = (const float*)d_in[13];
  const float* ln1_b   = (const float*)d_in[14];
  const float* ln2_g   = (const float*)d_in[15];
  const float* ln2_b   = (const float*)d_in[16];
  const float* lnf_g   = (const float*)d_in[17];
  const float* lnf_b   = (const float*)d_in[18];
  const float* w_head  = (const float*)d_in[19];
  const float* b_head  = (const float*)d_in[20];

  char* ws = (char*)d_ws;
  size_t off = 0;
  auto alloc = [&](size_t bytes) {
    char* p = ws + off;
    off += (bytes + 255) & ~(size_t)255;
    return p;
  };
  float* xf   = (float*)alloc((size_t)NROW * DIM * 4);
  bfu* hbuf   = (bfu*)alloc((size_t)NROW * DIM * 2);
  bfu* qkvb   = (bfu*)alloc((size_t)NROW * QKVS * 2);
  bfu* ob     = (bfu*)alloc((size_t)NROW * DIM * 2);
  bfu* ub     = (bfu*)alloc((size_t)NROW * FF * 2);
  bfu* vT     = (bfu*)alloc((size_t)NROW * DIM * 2);
  float* pbuf = (float*)alloc((size_t)2 * NROW * DIM * 4);   // K-split partials (proj & fc2)
  bfu* qkvT   = (bfu*)alloc((size_t)QKVS * DIM * 2);
  bfu* wpT    = (bfu*)alloc((size_t)DIM * DIM * 2);
  bfu* f1T    = (bfu*)alloc((size_t)DIM * FF * 2);
  bfu* f2T    = (bfu*)alloc((size_t)DIM * FF * 2);
  bfu* hT     = (bfu*)alloc((size_t)DIM * VOCAB * 2);
  float* nll  = (float*)alloc((size_t)NROW * 4);
  float* pmax = (float*)alloc((size_t)NROW * NCB * 4);
  float* psum = (float*)alloc((size_t)NROW * NCB * 4);
  if (off > ws_size) return;

  const size_t LDSB = 131072;  // gemm1024 BK64
  dim3 tb(32, 8);
  tkernel<<<dim3(VOCAB / 32, DIM / 32), tb, 0, stream>>>(w_head, hT, DIM, VOCAB);
  embed_kernel<<<NROW, 256, 0, stream>>>(idx, tok_emb, pos_emb, xf);

  float* logits = (float*)d_out;
  for (int l = 0; l < LAYERS; ++l) {
    const size_t wo = (size_t)l * DIM * DIM, fo = (size_t)l * DIM * FF;
    wtrans_kernel<<<12288, tb, 0, stream>>>(wq + wo, wk + wo, wv + wo, w_proj + wo,
                                            w_fc1 + fo, w_fc2 + fo, qkvT, wpT, f1T, f2T);
    if (l == 0)
      ln_kernel<<<NROW / 4, 256, 0, stream>>>(xf, ln1_g, ln1_b, hbuf);
    else
      lnfuse_kernel<<<NROW / 4, 256, 0, stream>>>(xf, pbuf, b_fc2 + (l - 1) * DIM,
                                                  ln1_g + l * DIM, ln1_b + l * DIM, hbuf);
    gemm_bt<5><<<dim3(QKVS / 128, NROW / 128), 256, 0, stream>>>(
        hbuf, qkvT, nullptr, nullptr, qkvb, vT, NROW, QKVS, DIM, DIM);
    attn_kernel<<<dim3(SEQ / 128, NH, NBATCH), 512, 0, stream>>>(qkvb, vT, ob);
    gemm_bt<6><<<dim3(DIM / 128, NROW / 128, 2), 256, 0, stream>>>(
        ob, wpT, nullptr, nullptr, pbuf, nullptr, NROW, DIM, DIM / 2, DIM);
    lnfuse_kernel<<<NROW / 4, 256, 0, stream>>>(xf, pbuf, b_proj + l * DIM,
                                                ln2_g + l * DIM, ln2_b + l * DIM, hbuf);
    gemm1024<1><<<dim3(FF / 256, NROW / 256), 1024, LDSB, stream>>>(
        hbuf, f1T, b_fc1 + l * FF, nullptr, ub, NROW, FF, DIM, 0, nullptr, nullptr);
    gemm_bt<6><<<dim3(DIM / 128, NROW / 128, 2), 256, 0, stream>>>(
        ub, f2T, nullptr, nullptr, pbuf, nullptr, NROW, DIM, FF / 2, FF);
  }

  lnfuse_kernel<<<NROW / 4, 256, 0, stream>>>(xf, pbuf, b_fc2 + 5 * DIM, lnf_g, lnf_b, hbuf);
  gemm1024<4><<<dim3(VOCAB / 256, NROW / 256), 1024, LDSB + 8192, stream>>>(
      hbuf, hT, b_head, nullptr, logits, NROW, VOCAB, DIM, 1, pmax, psum);
  nll_finish<<<NROW, 64, 0, stream>>>(pmax, psum, logits, targets, nll);
  loss_kernel<<<1, 256, 0, stream>>>(nll, logits);
}